// Round 5
// baseline (231.492 us; speedup 1.0000x reference)
//
#include <hip/hip_runtime.h>
#include <hip/hip_bf16.h>

// TaylorActivation: out = Horner(x; c[0..8]), c = w[:,0], order 8.
// x: (512, 65536) fp32 = 33,554,432 elems (2^25). Streaming elementwise,
// memory-bound. Min HBM traffic 256 MiB -> ~41 us @ 6.3 TB/s.
//
// R4 post-mortem: NT stores forced all 128 MiB of output to HBM inside the
// dispatch (WRITE_SIZE == output exactly) and we ran at 3.3 TB/s effective —
// half of m13's 6.29 TB/s plain-copy rate, with no pipe saturated.
// This round: exactly the proven copy idiom — plain cached loads, plain
// stores (dirty lines park in the 256 MiB L3, writeback deferred out of our
// window), straight-line VPT=4, block-strided fully-coalesced accesses.

typedef float f32x4 __attribute__((ext_vector_type(4)));

#define VPT 4  // f32x4 per thread (64 B)

__global__ __launch_bounds__(256) void taylor_poly_kernel(
    const f32x4* __restrict__ x,
    const float* __restrict__ w,   // 9 coefficients, c[i] = w[i]
    f32x4* __restrict__ out,
    int n4)
{
    const float c0 = w[0], c1 = w[1], c2 = w[2], c3 = w[3], c4 = w[4];
    const float c5 = w[5], c6 = w[6], c7 = w[7], c8 = w[8];

    const int base = blockIdx.x * (256 * VPT) + threadIdx.x;

    f32x4 v[VPT];

    // Loads issued back-to-back (per-access predication; for n = 2^25 and
    // grid = n4/1024 every access is in-bounds and the cmps fold to uniform).
#pragma unroll
    for (int k = 0; k < VPT; ++k) {
        int i = base + k * 256;
        if (i < n4) v[k] = x[i];
    }

#pragma unroll
    for (int k = 0; k < VPT; ++k) {
#pragma unroll
        for (int e = 0; e < 4; ++e) {
            float xv = v[k][e];
            float acc = fmaf(c8, xv, c7);
            acc = fmaf(acc, xv, c6);
            acc = fmaf(acc, xv, c5);
            acc = fmaf(acc, xv, c4);
            acc = fmaf(acc, xv, c3);
            acc = fmaf(acc, xv, c2);
            acc = fmaf(acc, xv, c1);
            acc = fmaf(acc, xv, c0);
            v[k][e] = acc;
        }
    }

#pragma unroll
    for (int k = 0; k < VPT; ++k) {
        int i = base + k * 256;
        if (i < n4) out[i] = v[k];   // plain store: L3 dirty-allocate
    }
}

extern "C" void kernel_launch(void* const* d_in, const int* in_sizes, int n_in,
                              void* d_out, int out_size, void* d_ws, size_t ws_size,
                              hipStream_t stream) {
    const float* x = (const float*)d_in[0];
    const float* w = (const float*)d_in[1];
    float* out = (float*)d_out;

    int n = in_sizes[0];          // 33,554,432 = 2^25
    int n4 = n >> 2;              // 8,388,608 f32x4

    const int block = 256;
    const int elems_per_block = block * VPT;                  // 1024 vec4 / block
    int grid = (n4 + elems_per_block - 1) / elems_per_block;  // 8192

    taylor_poly_kernel<<<grid, block, 0, stream>>>(
        (const f32x4*)x, w, (f32x4*)out, n4);
}